// Round 16
// baseline (241.382 us; speedup 1.0000x reference)
//
#include <hip/hip_runtime.h>
#include <hip/hip_cooperative_groups.h>
#include <math.h>

namespace cg = cooperative_groups;

#define NROWS 262144
#define DIM   256
#define NC    64
#define CD    (NC*DIM)       // 16384
#define NBLK  512            // main-phase blocks, 512 rows each

// ws float-offset layout:
//  cent_new [16384]      @ 0
//  abs_part [512]        @ 16384
//  pair_part[64]         @ 16896
//  s_part   [512*64]     @ 16960
//  s_stage2 [16*64]      @ 49728
//  partials [512*16384]  @ 50752   (ushort bf16: 16.8 MB)
#define OFF_CENT   0
#define OFF_ABS    16384
#define OFF_PAIR   16896
#define OFF_SPART  16960
#define OFF_SST2   49728
#define OFF_PART   50752

typedef short  bf16x8 __attribute__((ext_vector_type(8)));
typedef float  f32x16 __attribute__((ext_vector_type(16)));

// DPP 64-lane sum: after these 6 adds, lane 63 holds the full sum.
#define DPP_ADD(v, ctrl) \
    ((v) + __int_as_float(__builtin_amdgcn_update_dpp(0, __float_as_int(v), (ctrl), 0xf, 0xf, true)))

__device__ __forceinline__ float dpp_sum64(float v) {
    v = DPP_ADD(v, 0x111);
    v = DPP_ADD(v, 0x112);
    v = DPP_ADD(v, 0x114);
    v = DPP_ADD(v, 0x118);
    v = DPP_ADD(v, 0x142);
    v = DPP_ADD(v, 0x143);
    return v;                // lane 63 = total
}

__device__ __forceinline__ unsigned int bf16rne2(float lo, float hi) {
    unsigned int ul = __float_as_uint(lo);
    ul = (ul + 0x7FFFu + ((ul >> 16) & 1u)) >> 16;
    unsigned int uh = __float_as_uint(hi);
    uh = (uh + 0x7FFFu + ((uh >> 16) & 1u)) & 0xFFFF0000u;
    return ul | uh;
}
__device__ __forceinline__ unsigned short bf16rne1(float v) {
    unsigned int x = __float_as_uint(v);
    return (unsigned short)((x + 0x7FFFu + ((x >> 16) & 1u)) >> 16);
}
__device__ __forceinline__ float bflo(unsigned int u) { return __uint_as_float(u << 16); }
__device__ __forceinline__ float bfhi(unsigned int u) { return __uint_as_float(u & 0xFFFF0000u); }
__device__ __forceinline__ float bfup(unsigned short u) { return __uint_as_float(((unsigned int)u) << 16); }

// MFMA for one 64-row chunk (4 ksteps x 2 class-tiles); A-frags self-built.
__device__ __forceinline__ void do_mfma_chunk(const unsigned short* pb,
                                              const int* tgts, int rbase,
                                              int lane, int d0,
                                              f32x16& a0r, f32x16& a1r)
{
    const int g8  = (lane >> 5) << 3;
    const int cA  = lane & 31;
    const int cB  = 32 + cA;
    const int col = d0 + cA;
    #pragma unroll
    for (int ks = 0; ks < 4; ++ks) {
        const int rA = rbase + ks * 16 + g8;
        const int t0 = tgts[rA+0], t1 = tgts[rA+1], t2 = tgts[rA+2], t3 = tgts[rA+3];
        const int t4 = tgts[rA+4], t5 = tgts[rA+5], t6 = tgts[rA+6], t7 = tgts[rA+7];
        union { unsigned int u[4]; bf16x8 v; } A0, A1, B;
        A0.u[0] = ((t0==cA)?0x3F80u:0u) | (((t1==cA)?0x3F80u:0u) << 16);
        A0.u[1] = ((t2==cA)?0x3F80u:0u) | (((t3==cA)?0x3F80u:0u) << 16);
        A0.u[2] = ((t4==cA)?0x3F80u:0u) | (((t5==cA)?0x3F80u:0u) << 16);
        A0.u[3] = ((t6==cA)?0x3F80u:0u) | (((t7==cA)?0x3F80u:0u) << 16);
        A1.u[0] = ((t0==cB)?0x3F80u:0u) | (((t1==cB)?0x3F80u:0u) << 16);
        A1.u[1] = ((t2==cB)?0x3F80u:0u) | (((t3==cB)?0x3F80u:0u) << 16);
        A1.u[2] = ((t4==cB)?0x3F80u:0u) | (((t5==cB)?0x3F80u:0u) << 16);
        A1.u[3] = ((t6==cB)?0x3F80u:0u) | (((t7==cB)?0x3F80u:0u) << 16);
        const int kr = ks * 16 + g8;
        #pragma unroll
        for (int p = 0; p < 4; ++p) {
            const unsigned int lo = pb[(kr + 2*p    ) * 256 + col];
            const unsigned int hi = pb[(kr + 2*p + 1) * 256 + col];
            B.u[p] = lo | (hi << 16);
        }
        a0r = __builtin_amdgcn_mfma_f32_32x32x16_bf16(A0.v, B.v, a0r, 0, 0, 0);
        a1r = __builtin_amdgcn_mfma_f32_32x32x16_bf16(A1.v, B.v, a1r, 0, 0, 0);
    }
}

// phase: -1 = all phases with grid.sync (cooperative); 0..3 = single phase.
__global__ __launch_bounds__(512, 4)
void k_fused(const float* __restrict__ pred, const float* __restrict__ cent,
             const float* __restrict__ count, const float* __restrict__ dist,
             const float* __restrict__ cw, const int* __restrict__ tgt,
             float* __restrict__ ws, float* __restrict__ out, int phase)
{
    cg::grid_group grid = cg::this_grid();

    __shared__ unsigned short pbf[64 * 256];   // 32 KB
    __shared__ unsigned short cbf[NC * 256];   // 32 KB
    __shared__ int   tgt_s[512];
    __shared__ float inv_s[64];
    __shared__ float vec_s[512];
    __shared__ float sw_s[8][64];
    __shared__ float red2[16][32];
    __shared__ float sred[8][64];

    const int tid  = threadIdx.x;
    const int w    = tid >> 6;
    const int lane = tid & 63;

    // ================= PHASE M: streaming MFMA scatter-add (R14 verbatim) ====
    if (phase <= 0) {
        const int base = blockIdx.x * 512;
        tgt_s[tid] = tgt[base + tid];
        if (tid < 64) inv_s[tid] = 1.0f / count[tid];
        {
            const float2* c2 = (const float2*)cent;
            unsigned int* cb32 = (unsigned int*)cbf;
            #pragma unroll
            for (int i = 0; i < 16; ++i) {
                const int o = i * 512 + tid;
                const float2 cf = c2[o];
                cb32[o] = bf16rne2(cf.x, cf.y);
            }
        }
        __syncthreads();

        const float4* pred4 = (const float4*)pred;
        const int d0 = w * 32;

        f32x16 acc0 = {};
        f32x16 acc1 = {};

        #pragma unroll 1
        for (int ch = 0; ch < 8; ++ch) {
            const size_t gr = (size_t)(base + ch * 64) * 64 + lane;
            float4 p0 = pred4[gr + (size_t)( 0 + w) * 64];
            float4 p1 = pred4[gr + (size_t)( 8 + w) * 64];
            float4 p2 = pred4[gr + (size_t)(16 + w) * 64];
            float4 p3 = pred4[gr + (size_t)(24 + w) * 64];
            float4 p4 = pred4[gr + (size_t)(32 + w) * 64];
            float4 p5 = pred4[gr + (size_t)(40 + w) * 64];
            float4 p6 = pred4[gr + (size_t)(48 + w) * 64];
            float4 p7 = pred4[gr + (size_t)(56 + w) * 64];

#define ROW(pp, i)                                                             \
            {                                                                  \
                const int rc = 8*(i) + w;                                      \
                const int r  = ch * 64 + rc;                                   \
                const int c  = tgt_s[r];                                       \
                const float iv = inv_s[c];                                     \
                const uint2 cu = *(const uint2*)&cbf[c * 256 + lane * 4];      \
                const float dx = bflo(cu.x) - pp.x * iv;                       \
                const float dy = bfhi(cu.x) - pp.y * iv;                       \
                const float dz = bflo(cu.y) - pp.z * iv;                       \
                const float dw = bfhi(cu.y) - pp.w * iv;                       \
                float ss = dx*dx + dy*dy + dz*dz + dw*dw;                      \
                ss = dpp_sum64(ss);                                            \
                if (lane == 63) vec_s[r] = sqrtf(ss);                          \
                *(uint2*)&pbf[rc * 256 + lane * 4] =                           \
                    make_uint2(bf16rne2(pp.x, pp.y), bf16rne2(pp.z, pp.w));    \
            }
            ROW(p0, 0) ROW(p1, 1) ROW(p2, 2) ROW(p3, 3)
            ROW(p4, 4) ROW(p5, 5) ROW(p6, 6) ROW(p7, 7)
#undef ROW
            __syncthreads();
            do_mfma_chunk(pbf, tgt_s, ch * 64, lane, d0, acc0, acc1);
            __syncthreads();
        }

        unsigned short* pp = (unsigned short*)(ws + OFF_PART) + (size_t)blockIdx.x * CD;
        const int dim = d0 + (lane & 31);
        #pragma unroll
        for (int reg = 0; reg < 16; ++reg) {
            const int crow = (reg & 3) + 8 * (reg >> 2) + 4 * (lane >> 5);
            pp[(     crow) * 256 + dim] = bf16rne1(acc0[reg]);
            pp[(32 + crow) * 256 + dim] = bf16rne1(acc1[reg]);
        }

        {
            const float vv = vec_s[w * 64 + lane];
            const int   cc = tgt_s[w * 64 + lane];
            float accs = 0.f;
            for (int k = 0; k < NC; ++k) {
                float sel = (cc == k) ? vv : 0.f;
                sel = dpp_sum64(sel);
                const float tot = __shfl(sel, 63, 64);
                accs += (lane == k) ? tot : 0.f;
            }
            sw_s[w][lane] = accs;
        }
        __syncthreads();
        if (w == 0) {
            float s = 0.f;
            #pragma unroll
            for (int q = 0; q < 8; ++q) s += sw_s[q][lane];
            ws[OFF_SPART + blockIdx.x * 64 + lane] = s;
        }
    }

    if (phase < 0) grid.sync();

    // ================= PHASE R: wide reduce + build cent_new/abs/s_stage2 ====
    if (phase < 0 || phase == 1) {
        const int b  = blockIdx.x;
        const int eo = tid & 31;
        const int g  = tid >> 5;                   // 0..15
        const int e  = b * 32 + eo;
        const unsigned short* pp = (const unsigned short*)(ws + OFF_PART);
        float s = 0.f;
        const int p0 = g * 32;
        #pragma unroll 8
        for (int p = p0; p < p0 + 32; ++p) s += bfup(pp[(size_t)p * CD + e]);
        red2[g][eo] = s;
        __syncthreads();
        if (tid < 32) {
            float tot = 0.f;
            #pragma unroll
            for (int q = 0; q < 16; ++q) tot += red2[q][tid];
            const int e2 = b * 32 + tid;
            const int c  = e2 >> 8;
            const float val = cent[e2] + tot / count[c];
            ws[OFF_CENT + e2] = val;
            vec_s[tid] = fabsf(val);
        }
        __syncthreads();
        if (tid < 64) {
            float a = (tid < 32) ? vec_s[tid] : 0.f;
            a = dpp_sum64(a);
            if (tid == 63) ws[OFF_ABS + b] = a;
        }
        if (b >= 496) {                            // 16 blocks: s_part reduce
            const int q  = b - 496;                // 0..15
            const int c  = tid & 63;
            const int rw = tid >> 6;               // 0..7
            float s2 = 0.f;
            #pragma unroll
            for (int i = 0; i < 4; ++i)
                s2 += ws[OFF_SPART + (q * 32 + rw * 4 + i) * 64 + c];
            sred[rw][c] = s2;
            __syncthreads();
            if (tid < 64) {
                float sv = 0.f;
                #pragma unroll
                for (int r = 0; r < 8; ++r) sv += sred[r][tid];
                ws[OFF_SST2 + q * 64 + tid] = sv;
            }
        }
    }

    if (phase < 0) grid.sync();

    // ================= PHASE P: pairwise terms (blocks 0..63) ================
    if ((phase < 0 || phase == 2) && blockIdx.x < 64) {
        const int i = blockIdx.x;
        if (tid < 64) {
            float sv = 0.f;
            #pragma unroll
            for (int q = 0; q < 16; ++q) sv += ws[OFF_SST2 + q * 64 + tid];
            inv_s[tid] = sqrtf(dist[tid] + sv) / count[tid];   // s_final
        }
        __syncthreads();
        const float4* c4 = (const float4*)(ws + OFF_CENT);
        const float si = inv_s[i];
        const float4 ci = c4[i * 64 + lane];
        float acc = 0.f;                            // meaningful on lane 63
        for (int j = w; j < NC; j += 8) {
            if (j == i) continue;
            const float4 cj = c4[j * 64 + lane];
            const float dx = ci.x - cj.x, dy = ci.y - cj.y;
            const float dz = ci.z - cj.z, dw = ci.w - cj.w;
            float ss = dx*dx + dy*dy + dz*dz + dw*dw;
            ss = dpp_sum64(ss);
            if (lane == 63) acc += cw[i * NC + j] * (si + inv_s[j]) / sqrtf(ss);
        }
        if (lane == 63) sw_s[w][0] = acc;
        __syncthreads();
        if (tid == 0) {
            float ps = 0.f;
            #pragma unroll
            for (int q = 0; q < 8; ++q) ps += sw_s[q][0];
            ws[OFF_PAIR + i] = ps;
        }
    }

    if (phase < 0) grid.sync();

    // ================= PHASE F: final scalar (block 0) =======================
    if ((phase < 0 || phase == 3) && blockIdx.x == 0) {
        float a = ws[OFF_ABS + tid];                       // 512 entries
        float p = (tid < 64) ? ws[OFF_PAIR + tid] : 0.f;
        a = dpp_sum64(a);
        p = dpp_sum64(p);
        if (lane == 63) { sw_s[w][0] = a; sw_s[w][1] = p; }
        __syncthreads();
        if (tid == 0) {
            float as = 0.f, ps = 0.f;
            #pragma unroll
            for (int q = 0; q < 8; ++q) { as += sw_s[q][0]; ps += sw_s[q][1]; }
            out[0] = ps / 64.0f * 63.0f + as * 1e-6f;
        }
    }
}

extern "C" void kernel_launch(void* const* d_in, const int* in_sizes, int n_in,
                              void* d_out, int out_size, void* d_ws, size_t ws_size,
                              hipStream_t stream)
{
    const float* pred  = (const float*)d_in[0];
    const float* cent  = (const float*)d_in[1];
    const float* dist  = (const float*)d_in[2];
    const float* count = (const float*)d_in[3];
    const float* cw    = (const float*)d_in[4];
    const int*   tgt   = (const int*)d_in[5];
    float* ws  = (float*)d_ws;
    float* out = (float*)d_out;

    int phase_all = -1;
    void* args[] = { (void*)&pred, (void*)&cent, (void*)&count, (void*)&dist,
                     (void*)&cw, (void*)&tgt, (void*)&ws, (void*)&out,
                     (void*)&phase_all };
    hipError_t err = hipLaunchCooperativeKernel((const void*)k_fused,
                                                dim3(NBLK), dim3(512),
                                                args, 0, stream);
    if (err != hipSuccess) {
        // fallback: same kernel, phase-by-phase, plain launches (bit-identical)
        k_fused<<<NBLK, 512, 0, stream>>>(pred, cent, count, dist, cw, tgt, ws, out, 0);
        k_fused<<<NBLK, 512, 0, stream>>>(pred, cent, count, dist, cw, tgt, ws, out, 1);
        k_fused<<<64,   512, 0, stream>>>(pred, cent, count, dist, cw, tgt, ws, out, 2);
        k_fused<<<1,    512, 0, stream>>>(pred, cent, count, dist, cw, tgt, ws, out, 3);
    }
}

// Round 17
// 74.781 us; speedup vs baseline: 3.2278x; 3.2278x over previous
//
#include <hip/hip_runtime.h>
#include <math.h>

#define NROWS 262144
#define DIM   256
#define NC    64
#define CD    (NC*DIM)       // 16384
#define NBLK  512            // k_main blocks, 512 rows each

// ws float-offset layout:
//  cent_new [16384]      @ 0
//  abs_part [512]        @ 16384
//  pair_part[64]         @ 16896
//  s_part   [512*64]     @ 16960
//  s_stage2 [16*64]      @ 49728
//  partials [512*16384]  @ 50752   (ushort bf16: 16.8 MB)
#define OFF_CENT   0
#define OFF_ABS    16384
#define OFF_PAIR   16896
#define OFF_SPART  16960
#define OFF_SST2   49728
#define OFF_PART   50752

typedef short  bf16x8 __attribute__((ext_vector_type(8)));
typedef float  f32x16 __attribute__((ext_vector_type(16)));

// DPP 64-lane sum: after these 6 adds, lane 63 holds the full sum.
#define DPP_ADD(v, ctrl) \
    ((v) + __int_as_float(__builtin_amdgcn_update_dpp(0, __float_as_int(v), (ctrl), 0xf, 0xf, true)))

__device__ __forceinline__ float dpp_sum64(float v) {
    v = DPP_ADD(v, 0x111);
    v = DPP_ADD(v, 0x112);
    v = DPP_ADD(v, 0x114);
    v = DPP_ADD(v, 0x118);
    v = DPP_ADD(v, 0x142);
    v = DPP_ADD(v, 0x143);
    return v;                // lane 63 = total
}

__device__ __forceinline__ unsigned int bf16rne2(float lo, float hi) {
    unsigned int ul = __float_as_uint(lo);
    ul = (ul + 0x7FFFu + ((ul >> 16) & 1u)) >> 16;
    unsigned int uh = __float_as_uint(hi);
    uh = (uh + 0x7FFFu + ((uh >> 16) & 1u)) & 0xFFFF0000u;
    return ul | uh;
}
__device__ __forceinline__ unsigned short bf16rne1(float v) {
    unsigned int x = __float_as_uint(v);
    return (unsigned short)((x + 0x7FFFu + ((x >> 16) & 1u)) >> 16);
}
__device__ __forceinline__ float bflo(unsigned int u) { return __uint_as_float(u << 16); }
__device__ __forceinline__ float bfhi(unsigned int u) { return __uint_as_float(u & 0xFFFF0000u); }
__device__ __forceinline__ float bfup(unsigned short u) { return __uint_as_float(((unsigned int)u) << 16); }

// MFMA for one 64-row chunk (4 ksteps x 2 class-tiles); A-frags self-built.
__device__ __forceinline__ void do_mfma_chunk(const unsigned short* pb,
                                              const int* tgts, int rbase,
                                              int lane, int d0,
                                              f32x16& a0r, f32x16& a1r)
{
    const int g8  = (lane >> 5) << 3;
    const int cA  = lane & 31;
    const int cB  = 32 + cA;
    const int col = d0 + cA;
    #pragma unroll
    for (int ks = 0; ks < 4; ++ks) {
        const int rA = rbase + ks * 16 + g8;
        const int t0 = tgts[rA+0], t1 = tgts[rA+1], t2 = tgts[rA+2], t3 = tgts[rA+3];
        const int t4 = tgts[rA+4], t5 = tgts[rA+5], t6 = tgts[rA+6], t7 = tgts[rA+7];
        union { unsigned int u[4]; bf16x8 v; } A0, A1, B;
        A0.u[0] = ((t0==cA)?0x3F80u:0u) | (((t1==cA)?0x3F80u:0u) << 16);
        A0.u[1] = ((t2==cA)?0x3F80u:0u) | (((t3==cA)?0x3F80u:0u) << 16);
        A0.u[2] = ((t4==cA)?0x3F80u:0u) | (((t5==cA)?0x3F80u:0u) << 16);
        A0.u[3] = ((t6==cA)?0x3F80u:0u) | (((t7==cA)?0x3F80u:0u) << 16);
        A1.u[0] = ((t0==cB)?0x3F80u:0u) | (((t1==cB)?0x3F80u:0u) << 16);
        A1.u[1] = ((t2==cB)?0x3F80u:0u) | (((t3==cB)?0x3F80u:0u) << 16);
        A1.u[2] = ((t4==cB)?0x3F80u:0u) | (((t5==cB)?0x3F80u:0u) << 16);
        A1.u[3] = ((t6==cB)?0x3F80u:0u) | (((t7==cB)?0x3F80u:0u) << 16);
        const int kr = ks * 16 + g8;
        #pragma unroll
        for (int p = 0; p < 4; ++p) {
            const unsigned int lo = pb[(kr + 2*p    ) * 256 + col];
            const unsigned int hi = pb[(kr + 2*p + 1) * 256 + col];
            B.u[p] = lo | (hi << 16);
        }
        a0r = __builtin_amdgcn_mfma_f32_32x32x16_bf16(A0.v, B.v, a0r, 0, 0, 0);
        a1r = __builtin_amdgcn_mfma_f32_32x32x16_bf16(A1.v, B.v, a1r, 0, 0, 0);
    }
}

// ---- k_main: streaming MFMA scatter-add (R14 verbatim) ----
__global__ __launch_bounds__(512, 4)
void k_main(const float* __restrict__ pred, const float* __restrict__ cent,
            const float* __restrict__ count, const int* __restrict__ tgt,
            float* __restrict__ ws)
{
    __shared__ unsigned short pbf[64 * 256];   // 32 KB bf16 chunk [r][d]
    __shared__ unsigned short cbf[NC * 256];   // 32 KB bf16 centroids [c][d]
    __shared__ int   tgt_s[512];
    __shared__ float inv_s[64];
    __shared__ float vec_s[512];
    __shared__ float sw_s[8][64];

    const int tid  = threadIdx.x;
    const int w    = tid >> 6;        // 8 waves; wave owns dims [32w, 32w+32)
    const int lane = tid & 63;
    const int base = blockIdx.x * 512;

    tgt_s[tid] = tgt[base + tid];
    if (tid < 64) inv_s[tid] = 1.0f / count[tid];
    {
        const float2* c2 = (const float2*)cent;
        unsigned int* cb32 = (unsigned int*)cbf;
        #pragma unroll
        for (int i = 0; i < 16; ++i) {
            const int o = i * 512 + tid;
            const float2 cf = c2[o];
            cb32[o] = bf16rne2(cf.x, cf.y);
        }
    }
    __syncthreads();

    const float4* pred4 = (const float4*)pred;
    const int d0 = w * 32;

    f32x16 acc0 = {};   // classes [0,32)  x dims [d0,d0+32)
    f32x16 acc1 = {};   // classes [32,64) x dims [d0,d0+32)

    #pragma unroll 1
    for (int ch = 0; ch < 8; ++ch) {
        const size_t gr = (size_t)(base + ch * 64) * 64 + lane;
        float4 p0 = pred4[gr + (size_t)( 0 + w) * 64];
        float4 p1 = pred4[gr + (size_t)( 8 + w) * 64];
        float4 p2 = pred4[gr + (size_t)(16 + w) * 64];
        float4 p3 = pred4[gr + (size_t)(24 + w) * 64];
        float4 p4 = pred4[gr + (size_t)(32 + w) * 64];
        float4 p5 = pred4[gr + (size_t)(40 + w) * 64];
        float4 p6 = pred4[gr + (size_t)(48 + w) * 64];
        float4 p7 = pred4[gr + (size_t)(56 + w) * 64];

#define ROW(pp, i)                                                             \
        {                                                                      \
            const int rc = 8*(i) + w;                                          \
            const int r  = ch * 64 + rc;                                       \
            const int c  = tgt_s[r];                                           \
            const float iv = inv_s[c];                                         \
            const uint2 cu = *(const uint2*)&cbf[c * 256 + lane * 4];          \
            const float dx = bflo(cu.x) - pp.x * iv;                           \
            const float dy = bfhi(cu.x) - pp.y * iv;                           \
            const float dz = bflo(cu.y) - pp.z * iv;                           \
            const float dw = bfhi(cu.y) - pp.w * iv;                           \
            float ss = dx*dx + dy*dy + dz*dz + dw*dw;                          \
            ss = dpp_sum64(ss);                                                \
            if (lane == 63) vec_s[r] = sqrtf(ss);                              \
            *(uint2*)&pbf[rc * 256 + lane * 4] =                               \
                make_uint2(bf16rne2(pp.x, pp.y), bf16rne2(pp.z, pp.w));        \
        }
        ROW(p0, 0) ROW(p1, 1) ROW(p2, 2) ROW(p3, 3)
        ROW(p4, 4) ROW(p5, 5) ROW(p6, 6) ROW(p7, 7)
#undef ROW
        __syncthreads();
        do_mfma_chunk(pbf, tgt_s, ch * 64, lane, d0, acc0, acc1);
        __syncthreads();
    }

    // write bf16 partials (C/D layout: col=lane&31, row=(reg&3)+8*(reg>>2)+4*(lane>>5))
    unsigned short* pp = (unsigned short*)(ws + OFF_PART) + (size_t)blockIdx.x * CD;
    const int dim = d0 + (lane & 31);
    #pragma unroll
    for (int reg = 0; reg < 16; ++reg) {
        const int crow = (reg & 3) + 8 * (reg >> 2) + 4 * (lane >> 5);
        pp[(     crow) * 256 + dim] = bf16rne1(acc0[reg]);
        pp[(32 + crow) * 256 + dim] = bf16rne1(acc1[reg]);
    }

    // block-end per-class s reduction (no atomics)
    {
        const float vv = vec_s[w * 64 + lane];
        const int   cc = tgt_s[w * 64 + lane];
        float accs = 0.f;
        for (int k = 0; k < NC; ++k) {
            float sel = (cc == k) ? vv : 0.f;
            sel = dpp_sum64(sel);
            const float tot = __shfl(sel, 63, 64);
            accs += (lane == k) ? tot : 0.f;
        }
        sw_s[w][lane] = accs;
    }
    __syncthreads();
    if (w == 0) {
        float s = 0.f;
        #pragma unroll
        for (int q = 0; q < 8; ++q) s += sw_s[q][lane];
        ws[OFF_SPART + blockIdx.x * 64 + lane] = s;
    }
}

// ---- k_red2: fused wide reduce + build (R16 phase R, standalone) ----
// 512 blocks x 512 thr; block b fully reduces 32 elements; blocks 496..511
// additionally reduce s_part -> s_stage2.
__global__ __launch_bounds__(512)
void k_red2(const float* __restrict__ cent, const float* __restrict__ count,
            float* __restrict__ ws)
{
    __shared__ float red2[16][32];
    __shared__ float absl[32];
    __shared__ float sred[8][64];
    const int b = blockIdx.x, tid = threadIdx.x;

    const int eo = tid & 31;
    const int g  = tid >> 5;                   // 0..15
    const int e  = b * 32 + eo;
    const unsigned short* pp = (const unsigned short*)(ws + OFF_PART);
    float s = 0.f;
    const int p0 = g * 32;
    #pragma unroll 8
    for (int p = p0; p < p0 + 32; ++p) s += bfup(pp[(size_t)p * CD + e]);
    red2[g][eo] = s;
    __syncthreads();
    if (tid < 32) {
        float tot = 0.f;
        #pragma unroll
        for (int q = 0; q < 16; ++q) tot += red2[q][tid];
        const int e2 = b * 32 + tid;
        const int c  = e2 >> 8;
        const float val = cent[e2] + tot / count[c];
        ws[OFF_CENT + e2] = val;
        absl[tid] = fabsf(val);
    }
    __syncthreads();
    if (tid < 64) {
        float a = (tid < 32) ? absl[tid] : 0.f;
        a = dpp_sum64(a);
        if (tid == 63) ws[OFF_ABS + b] = a;
    }
    if (b >= 496) {                            // 16 blocks: s_part reduce
        const int q  = b - 496;                // 0..15
        const int c  = tid & 63;
        const int rw = tid >> 6;               // 0..7
        float s2 = 0.f;
        #pragma unroll
        for (int i = 0; i < 4; ++i)
            s2 += ws[OFF_SPART + (q * 32 + rw * 4 + i) * 64 + c];
        sred[rw][c] = s2;
        __syncthreads();
        if (tid < 64) {
            float sv = 0.f;
            #pragma unroll
            for (int r = 0; r < 8; ++r) sv += sred[r][tid];
            ws[OFF_SST2 + q * 64 + tid] = sv;
        }
    }
}

// ---- k_pairs: s_final prologue + pairwise terms (R16 phase P, standalone) ----
__global__ __launch_bounds__(512)
void k_pairs(const float* __restrict__ count, const float* __restrict__ dist,
             const float* __restrict__ cw, float* __restrict__ ws)
{
    __shared__ float sf_s[64];
    __shared__ float wsum[8];
    const int i = blockIdx.x, tid = threadIdx.x;
    const int w = tid >> 6, lane = tid & 63;

    if (tid < 64) {
        float sv = 0.f;
        #pragma unroll
        for (int q = 0; q < 16; ++q) sv += ws[OFF_SST2 + q * 64 + tid];
        sf_s[tid] = sqrtf(dist[tid] + sv) / count[tid];   // s_final
    }
    __syncthreads();
    const float4* c4 = (const float4*)(ws + OFF_CENT);
    const float si = sf_s[i];
    const float4 ci = c4[i * 64 + lane];
    float acc = 0.f;                            // meaningful on lane 63
    for (int j = w; j < NC; j += 8) {
        if (j == i) continue;
        const float4 cj = c4[j * 64 + lane];
        const float dx = ci.x - cj.x, dy = ci.y - cj.y;
        const float dz = ci.z - cj.z, dw = ci.w - cj.w;
        float ss = dx*dx + dy*dy + dz*dz + dw*dw;
        ss = dpp_sum64(ss);
        if (lane == 63) acc += cw[i * NC + j] * (si + sf_s[j]) / sqrtf(ss);
    }
    if (lane == 63) wsum[w] = acc;
    __syncthreads();
    if (tid == 0) {
        float ps = 0.f;
        #pragma unroll
        for (int q = 0; q < 8; ++q) ps += wsum[q];
        ws[OFF_PAIR + i] = ps;
    }
}

// ---- k_fin: final scalar (R16 phase F, standalone) ----
__global__ __launch_bounds__(512)
void k_fin(const float* __restrict__ ws, float* __restrict__ out)
{
    __shared__ float ra[8], rp[8];
    const int tid = threadIdx.x, w = tid >> 6, lane = tid & 63;
    float a = ws[OFF_ABS + tid];                       // 512 entries
    float p = (tid < 64) ? ws[OFF_PAIR + tid] : 0.f;
    a = dpp_sum64(a);
    p = dpp_sum64(p);
    if (lane == 63) { ra[w] = a; rp[w] = p; }
    __syncthreads();
    if (tid == 0) {
        float as = 0.f, ps = 0.f;
        #pragma unroll
        for (int q = 0; q < 8; ++q) { as += ra[q]; ps += rp[q]; }
        out[0] = ps / 64.0f * 63.0f + as * 1e-6f;
    }
}

extern "C" void kernel_launch(void* const* d_in, const int* in_sizes, int n_in,
                              void* d_out, int out_size, void* d_ws, size_t ws_size,
                              hipStream_t stream)
{
    const float* pred  = (const float*)d_in[0];
    const float* cent  = (const float*)d_in[1];
    const float* dist  = (const float*)d_in[2];
    const float* count = (const float*)d_in[3];
    const float* cw    = (const float*)d_in[4];
    const int*   tgt   = (const int*)d_in[5];
    float* ws  = (float*)d_ws;
    float* out = (float*)d_out;

    // no atomics anywhere -> no memset needed
    k_main <<<NBLK, 512, 0, stream>>>(pred, cent, count, tgt, ws);
    k_red2 <<<NBLK, 512, 0, stream>>>(cent, count, ws);
    k_pairs<<<NC,   512, 0, stream>>>(count, dist, cw, ws);
    k_fin  <<<1,    512, 0, stream>>>(ws, out);
}